// Round 6
// baseline (166.741 us; speedup 1.0000x reference)
//
#include <hip/hip_runtime.h>
#include <math.h>

#define N_NODES 10000
#define N_EDGES 320000
#define IN_DIM  128
#define HID     256
#define CAP     128      // bucket capacity; Poisson(32) => overflow prob ~0
#define NWB     64       // W-path blocks (gates+LSTM+Wc, block-local)
#define NFB     10       // fill blocks (counting sort, LDS-private hist)
#define NB1     (NWB + NFB)
#define EPB     (N_EDGES / NFB)   // 32000 edges per fill block
#define QPB     (EPB / 4)         // 8000 int4 quads per fill block

typedef __attribute__((ext_vector_type(8))) short frag_ab;
typedef __attribute__((ext_vector_type(4))) float frag_cd;

// ---------------- workspace layout (bytes) ----------------
// cursor @ 0       : 40,000    (final in-degree per node; plain stores)
// flag   @ 40,000  : 16        (fill-block sync counter; memset to 0)
// wct    @ 40,064  : 65,536    (WcT packed bf16x2 [n=256][64])
// bc     @ 105,600 : 1,024     (bp @ Wev)
// histG  @ 106,624 : 400,000   (per-fill-block histograms [NFB][N_NODES])
// bucket @ 506,624 : 5,120,000 (edge buckets)

__device__ __forceinline__ unsigned bf16rne(float f) {
    union { float f; unsigned u; } c; c.f = f;
    return (c.u + 0x7FFFu + ((c.u >> 16) & 1u)) >> 16;
}
__device__ __forceinline__ float sig_f(float x)  { return 1.f / (1.f + __expf(-x)); }
__device__ __forceinline__ float tanh_f(float x) { return 1.f - 2.f / (1.f + __expf(2.f * x)); }

// relaxed agent-scope store (write-through to device coherence point; round-4-proven)
__device__ __forceinline__ void wt_u32(unsigned* p, unsigned v) {
    __hip_atomic_store(p, v, __ATOMIC_RELAXED, __HIP_MEMORY_SCOPE_AGENT);
}
__device__ __forceinline__ void arrive(int* c) {
    __syncthreads();                 // drain this block's stores (vmcnt0 at barrier)
    if (threadIdx.x == 0)
        __hip_atomic_fetch_add(c, 1, __ATOMIC_RELAXED, __HIP_MEMORY_SCOPE_AGENT);
}
__device__ __forceinline__ void waitflag(int* c, int n) {
    if (threadIdx.x == 0) {
        while (__hip_atomic_load(c, __ATOMIC_RELAXED, __HIP_MEMORY_SCOPE_AGENT) < n)
            __builtin_amdgcn_s_sleep(2);
    }
    __syncthreads();
    asm volatile("" ::: "memory");   // no load hoisting above the flag
}

// ===== K1: W-path (blocks 0..63) | counting-sort fill (blocks 64..73) =====
__global__ __launch_bounds__(256, 2)
void k1_prep(const int* __restrict__ ei,
             const float* __restrict__ Wp, const float* __restrict__ bp,
             const float* __restrict__ wih, const float* __restrict__ whh,
             const float* __restrict__ b_ih, const float* __restrict__ b_hh,
             const float* __restrict__ iw,
             int* __restrict__ cursor, int* __restrict__ flag,
             unsigned* __restrict__ wct, float* __restrict__ bc,
             unsigned* __restrict__ histG, int* __restrict__ bucket) {
    __shared__ __align__(16) char smem_raw[57920];   // 56.6 KB -> 2 blocks/CU
    const int bid = blockIdx.x;
    const int t = threadIdx.x;

    if (bid < NWB) {
        // Block b owns gate columns: n_local = q*4+jj <-> global n = q*256 + 4b + jj.
        float (*aT)[260]  = (float(*)[260])smem_raw;               // [32k][256m] iw^T tile
        float (*bSt)[20]  = (float(*)[20])(smem_raw + 33280);      // [256k][16n] Wih+Whh
        float (*iwc)[260] = (float(*)[260])(smem_raw + 53760);     // [4jj][256r] iw columns
        // stage B (once): bSt[k][n_local] = (Wih+Whh)[n_global][k]  (lane-consecutive ✓)
        #pragma unroll
        for (int n = 0; n < 16; ++n) {
            int nrow = (n >> 2) * 256 + 4 * bid + (n & 3);
            bSt[t][n] = wih[nrow * 256 + t] + whh[nrow * 256 + t];
        }
        // gates GEMM: gates[256m][16n] = iw @ Bsum^T, 4m x 4n / thread
        const int mg = t >> 2, ng = t & 3;
        const int srow = t >> 3, sf4 = t & 7;      // coalesced staging map
        float acc[4][4] = {};
        for (int kt = 0; kt < 8; ++kt) {
            int k0 = kt * 32;
            __syncthreads();
            #pragma unroll
            for (int rr = 0; rr < 8; ++rr) {       // 8 lanes/row, 128B segments
                int row = srow + 32 * rr;
                float4 v = *(const float4*)&iw[row * 256 + k0 + 4 * sf4];
                aT[4 * sf4 + 0][row] = v.x; aT[4 * sf4 + 1][row] = v.y;
                aT[4 * sf4 + 2][row] = v.z; aT[4 * sf4 + 3][row] = v.w;
            }
            __syncthreads();
            if (kt == (bid >> 3)) {                // iw cols 4b..4b+3 live in this tile
                int c0 = (4 * bid) & 31;
                #pragma unroll
                for (int jj = 0; jj < 4; ++jj) iwc[jj][t] = aT[c0 + jj][t];
            }
            #pragma unroll 4
            for (int kk = 0; kk < 32; ++kk) {
                float4 a4 = *(const float4*)&aT[kk][4 * mg];
                float4 b4 = *(const float4*)&bSt[k0 + kk][4 * ng];
                float a[4] = {a4.x, a4.y, a4.z, a4.w};
                float b[4] = {b4.x, b4.y, b4.z, b4.w};
                #pragma unroll
                for (int i = 0; i < 4; ++i)
                    #pragma unroll
                    for (int j = 0; j < 4; ++j)
                        acc[i][j] = fmaf(a[i], b[j], acc[i][j]);
            }
        }
        // gates -> LDS (reuse aT region; aT dead)
        float (*gates_lds)[17] = (float(*)[17])smem_raw;           // [256][17]
        float (*wevc)[260]     = (float(*)[260])(smem_raw + 33280);// [4jj][256k]
        __syncthreads();
        #pragma unroll
        for (int i = 0; i < 4; ++i)
            #pragma unroll
            for (int j = 0; j < 4; ++j)
                gates_lds[4 * mg + i][4 * ng + j] = acc[i][j];
        __syncthreads();
        // LSTM nonlinearity (iw column from LDS, no global gather)
        {
            int r = t;
            #pragma unroll
            for (int jj = 0; jj < 4; ++jj) {
                int jcol = 4 * bid + jj;
                float gi = gates_lds[r][0  + jj] + b_ih[jcol]       + b_hh[jcol];
                float gf = gates_lds[r][4  + jj] + b_ih[256 + jcol] + b_hh[256 + jcol];
                float gg = gates_lds[r][8  + jj] + b_ih[512 + jcol] + b_hh[512 + jcol];
                float go = gates_lds[r][12 + jj] + b_ih[768 + jcol] + b_hh[768 + jcol];
                float c  = sig_f(gf) * iwc[jj][r] + sig_f(gi) * tanh_f(gg);
                wevc[jj][r] = sig_f(go) * tanh_f(c);
            }
        }
        // Wc via LDS-staged Wp tiles (coalesced global loads)
        float (*wpT)[132] = (float(*)[132])smem_raw;               // [32kk][128a+pad]
        const int a2 = t & 63, jj = t >> 6;
        float c0 = 0.f, c1 = 0.f;
        for (int kt2 = 0; kt2 < 8; ++kt2) {
            int k0 = kt2 * 32;
            __syncthreads();                       // wpT reuse guard (also closes LSTM)
            #pragma unroll
            for (int ri = 0; ri < 4; ++ri) {
                int a = srow + 32 * ri;            // 0..127
                float4 v = *(const float4*)&Wp[a * 256 + k0 + 4 * sf4];
                wpT[4 * sf4 + 0][a] = v.x; wpT[4 * sf4 + 1][a] = v.y;
                wpT[4 * sf4 + 2][a] = v.z; wpT[4 * sf4 + 3][a] = v.w;
            }
            __syncthreads();
            #pragma unroll 8
            for (int kk = 0; kk < 32; ++kk) {
                float2 wv = *(const float2*)&wpT[kk][2 * a2];
                float wev = wevc[jj][k0 + kk];     // wave-uniform broadcast
                c0 = fmaf(wv.x, wev, c0);
                c1 = fmaf(wv.y, wev, c1);
            }
        }
        wct[(4 * bid + jj) * 64 + a2] = bf16rne(c0) | (bf16rne(c1) << 16);
        if (t < 4) {   // bias column: bc[4b+t] = bp . wevc[t]
            float s = 0.f;
            #pragma unroll 4
            for (int k4 = 0; k4 < 64; ++k4) {
                float4 b4 = *(const float4*)&bp[4 * k4];
                float4 w4 = *(const float4*)&wevc[t][4 * k4];
                s = fmaf(b4.x, w4.x, fmaf(b4.y, w4.y, fmaf(b4.z, w4.z, fmaf(b4.w, w4.w, s))));
            }
            bc[4 * bid + t] = s;
        }
    } else {
        // ===== counting-sort fill: zero device-scope atomics =====
        const int fb = bid - NWB;                  // 0..9
        unsigned* hist = (unsigned*)smem_raw;      // [10000] LDS
        for (int i = t; i < N_NODES; i += 256) hist[i] = 0;
        __syncthreads();
        const int* dsts = ei + N_EDGES;
        const int q0 = fb * QPB;                   // int4 quad base
        // pass A: LDS histogram of this block's 32000 dsts
        #pragma unroll 4
        for (int it = 0; it < 32; ++it) {
            int idx = it * 256 + t;
            if (idx < QPB) {
                int4 d4 = *(const int4*)&dsts[(q0 + idx) * 4];
                atomicAdd(&hist[d4.x], 1u);
                atomicAdd(&hist[d4.y], 1u);
                atomicAdd(&hist[d4.z], 1u);
                atomicAdd(&hist[d4.w], 1u);
            }
        }
        __syncthreads();
        // publish per-block histogram (write-through) and sync the 10 fill blocks
        for (int i = t; i < N_NODES; i += 256)
            wt_u32(&histG[fb * N_NODES + i], hist[i]);
        arrive(flag);
        waitflag(flag, NFB);
        // exact base per bin = sum of earlier blocks' counts; totals -> cursor
        #pragma unroll 4
        for (int i = t; i < N_NODES; i += 256) {
            unsigned base = 0, total = 0;
            #pragma unroll
            for (int b = 0; b < NFB; ++b) {
                unsigned h = histG[b * N_NODES + i];
                base += (b < fb) ? h : 0u;
                total += h;
            }
            hist[i] = base;
            if ((unsigned)(i - fb * 1000) < 1000u) cursor[i] = (int)total;
        }
        __syncthreads();
        // pass B: place via LDS rank (plain scattered stores, no global RMW)
        #pragma unroll 4
        for (int it = 0; it < 32; ++it) {
            int idx = it * 256 + t;
            if (idx < QPB) {
                int4 s4 = *(const int4*)&ei[(q0 + idx) * 4];
                int4 d4 = *(const int4*)&dsts[(q0 + idx) * 4];
                unsigned p;
                p = atomicAdd(&hist[d4.x], 1u); if (p < CAP) bucket[d4.x * CAP + p] = s4.x;
                p = atomicAdd(&hist[d4.y], 1u); if (p < CAP) bucket[d4.y * CAP + p] = s4.y;
                p = atomicAdd(&hist[d4.z], 1u); if (p < CAP) bucket[d4.z * CAP + p] = s4.z;
                p = atomicAdd(&hist[d4.w], 1u); if (p < CAP) bucket[d4.w * CAP + p] = s4.w;
            }
        }
    }
}

// ===== K2: per-tile aggregation (fp32 gathers from x) + MFMA out (unchanged) =====
__global__ __launch_bounds__(256)
void k2_agg_out(const float* __restrict__ x, const int* __restrict__ cursor,
                const int* __restrict__ bucket, const unsigned* __restrict__ wct,
                const float* __restrict__ bc, const float* __restrict__ b_gcn,
                float* __restrict__ out) {
    __shared__ unsigned y_lds[16][64];   // bf16x2 rows
    __shared__ float rs_lds[16];
    const int t = threadIdx.x;
    const int tile = blockIdx.x;
    const int w = t >> 6, lane = t & 63;
    const int q = lane >> 4, ln = lane & 15;
    const float2* x2 = (const float2*)x;

    for (int vi = 0; vi < 4; ++vi) {
        int r = vi * 4 + w;
        int v = tile * 16 + r;
        int cntv = cursor[v];
        float dv = rsqrtf((float)(cntv + 1));
        int cnt2 = cntv > CAP ? CAP : cntv;
        float2 sv = x2[v * 64 + lane];
        float acc0 = dv * sv.x, acc1 = dv * sv.y, wsum = dv;
        const int4* bkt4 = (const int4*)&bucket[v * CAP];
        int j = 0;
        for (; j + 8 <= cnt2; j += 8) {
            int4 sa = bkt4[j >> 2];
            int4 sb = bkt4[(j >> 2) + 1];
            float w0 = rsqrtf((float)(cursor[sa.x] + 1));
            float w1 = rsqrtf((float)(cursor[sa.y] + 1));
            float w2 = rsqrtf((float)(cursor[sa.z] + 1));
            float w3 = rsqrtf((float)(cursor[sa.w] + 1));
            float w4 = rsqrtf((float)(cursor[sb.x] + 1));
            float w5 = rsqrtf((float)(cursor[sb.y] + 1));
            float w6 = rsqrtf((float)(cursor[sb.z] + 1));
            float w7 = rsqrtf((float)(cursor[sb.w] + 1));
            float2 r0 = x2[sa.x * 64 + lane];
            float2 r1 = x2[sa.y * 64 + lane];
            float2 r2 = x2[sa.z * 64 + lane];
            float2 r3 = x2[sa.w * 64 + lane];
            float2 r4 = x2[sb.x * 64 + lane];
            float2 r5 = x2[sb.y * 64 + lane];
            float2 r6 = x2[sb.z * 64 + lane];
            float2 r7 = x2[sb.w * 64 + lane];
            acc0 = fmaf(w0, r0.x, acc0); acc1 = fmaf(w0, r0.y, acc1);
            acc0 = fmaf(w1, r1.x, acc0); acc1 = fmaf(w1, r1.y, acc1);
            acc0 = fmaf(w2, r2.x, acc0); acc1 = fmaf(w2, r2.y, acc1);
            acc0 = fmaf(w3, r3.x, acc0); acc1 = fmaf(w3, r3.y, acc1);
            acc0 = fmaf(w4, r4.x, acc0); acc1 = fmaf(w4, r4.y, acc1);
            acc0 = fmaf(w5, r5.x, acc0); acc1 = fmaf(w5, r5.y, acc1);
            acc0 = fmaf(w6, r6.x, acc0); acc1 = fmaf(w6, r6.y, acc1);
            acc0 = fmaf(w7, r7.x, acc0); acc1 = fmaf(w7, r7.y, acc1);
            wsum += w0 + w1 + w2 + w3 + w4 + w5 + w6 + w7;
        }
        for (; j < cnt2; ++j) {
            int s = bucket[v * CAP + j];
            float ws = rsqrtf((float)(cursor[s] + 1));
            float2 rv = x2[s * 64 + lane];
            acc0 = fmaf(ws, rv.x, acc0); acc1 = fmaf(ws, rv.y, acc1);
            wsum += ws;
        }
        y_lds[r][lane] = bf16rne(dv * acc0) | (bf16rne(dv * acc1) << 16);
        if (lane == 0) rs_lds[r] = dv * wsum;
    }
    __syncthreads();

    const int4* ya   = (const int4*)&y_lds[0][0];
    const int4* wct4 = (const int4*)wct;
    union { int4 v; frag_ab f; } a[4];
    #pragma unroll
    for (int kc = 0; kc < 4; ++kc)
        a[kc].v = ya[ln * 16 + kc * 4 + q];
    float rsv[4];
    #pragma unroll
    for (int r = 0; r < 4; ++r) rsv[r] = rs_lds[q * 4 + r];
    #pragma unroll
    for (int i = 0; i < 4; ++i) {
        int n0 = (w + 4 * i) * 16;
        union { int4 v; frag_ab f; } b[4];
        #pragma unroll
        for (int kc = 0; kc < 4; ++kc)
            b[kc].v = wct4[(n0 + ln) * 16 + kc * 4 + q];
        frag_cd accd = {0.f, 0.f, 0.f, 0.f};
        #pragma unroll
        for (int kc = 0; kc < 4; ++kc)
            accd = __builtin_amdgcn_mfma_f32_16x16x32_bf16(a[kc].f, b[kc].f, accd, 0, 0, 0);
        int n = n0 + ln;
        float bcv = bc[n], bgv = b_gcn[n];
        #pragma unroll
        for (int r = 0; r < 4; ++r) {
            int m = tile * 16 + q * 4 + r;
            out[m * HID + n] = accd[r] + rsv[r] * bcv + bgv;
        }
    }
}

extern "C" void kernel_launch(void* const* d_in, const int* in_sizes, int n_in,
                              void* d_out, int out_size, void* d_ws, size_t ws_size,
                              hipStream_t stream) {
    const float* x     = (const float*)d_in[0];
    const int*   ei    = (const int*)d_in[1];
    const float* Wp    = (const float*)d_in[2];
    const float* bp    = (const float*)d_in[3];
    const float* W_ih  = (const float*)d_in[4];
    const float* W_hh  = (const float*)d_in[5];
    const float* b_ih  = (const float*)d_in[6];
    const float* b_hh  = (const float*)d_in[7];
    const float* iw    = (const float*)d_in[8];
    const float* b_gcn = (const float*)d_in[9];
    float* out = (float*)d_out;

    char* ws = (char*)d_ws;
    int*      cursor = (int*)     (ws + 0);
    int*      flag   = (int*)     (ws + 40000);
    unsigned* wct    = (unsigned*)(ws + 40064);
    float*    bc     = (float*)   (ws + 105600);
    unsigned* histG  = (unsigned*)(ws + 106624);
    int*      bucket = (int*)     (ws + 506624);

    hipMemsetAsync(flag, 0, 16, stream);   // only the 10-block sync counter

    k1_prep<<<NB1, 256, 0, stream>>>(ei, Wp, bp, W_ih, W_hh, b_ih, b_hh, iw,
                                     cursor, flag, wct, bc, histG, bucket);
    k2_agg_out<<<625, 256, 0, stream>>>(x, cursor, bucket, wct, bc, b_gcn, out);
}

// Round 7
// 150.444 us; speedup vs baseline: 1.1083x; 1.1083x over previous
//
#include <hip/hip_runtime.h>
#include <math.h>

#define N_NODES 10000
#define N_EDGES 320000
#define IN_DIM  128
#define HID     256
#define CAP     128      // bucket capacity; Poisson(32) => overflow prob ~0
#define NWB     64       // W-path blocks (gates+LSTM+Wc, block-local)
#define NFB     448      // fill blocks (wide, device-scope atomics: ~12us measured r5)
#define NXB     128      // x->bf16 convert blocks
#define NB1     (NWB + NFB + NXB)   // 640

typedef __attribute__((ext_vector_type(8))) short frag_ab;
typedef __attribute__((ext_vector_type(4))) float frag_cd;

// ---------------- workspace layout (bytes) ----------------
// cursor @ 0         : 40,000    (in-degree counters, atomicAdd; memset to 0)
// wct    @ 40,064    : 65,536    (WcT packed bf16x2 [n=256][64])
// bc     @ 105,600   : 1,024     (bp @ Wev)
// xb     @ 106,624   : 2,560,000 (x packed bf16x2 -> L2-resident gather source)
// bucket @ 2,666,624 : 5,120,000 (edge buckets)

__device__ __forceinline__ unsigned bf16rne(float f) {
    union { float f; unsigned u; } c; c.f = f;
    return (c.u + 0x7FFFu + ((c.u >> 16) & 1u)) >> 16;
}
__device__ __forceinline__ float sig_f(float x)  { return 1.f / (1.f + __expf(-x)); }
__device__ __forceinline__ float tanh_f(float x) { return 1.f - 2.f / (1.f + __expf(2.f * x)); }

// ===== K1: W-path (0..63) | fill (64..511) | x->bf16 (512..639) =====
__global__ __launch_bounds__(256, 2)
void k1_prep(const float* __restrict__ x, const int* __restrict__ ei,
             const float* __restrict__ Wp, const float* __restrict__ bp,
             const float* __restrict__ wih, const float* __restrict__ whh,
             const float* __restrict__ b_ih, const float* __restrict__ b_hh,
             const float* __restrict__ iw,
             int* __restrict__ cursor, unsigned* __restrict__ wct,
             float* __restrict__ bc, unsigned* __restrict__ xb,
             int* __restrict__ bucket) {
    __shared__ __align__(16) char smem_raw[57920];   // 56.6 KB -> 2 blocks/CU
    const int bid = blockIdx.x;
    const int t = threadIdx.x;

    if (bid < NWB) {
        // Block b owns gate columns: n_local = q*4+jj <-> global n = q*256 + 4b + jj.
        float (*aT)[260]  = (float(*)[260])smem_raw;               // [32k][256m] iw^T tile
        float (*bSt)[20]  = (float(*)[20])(smem_raw + 33280);      // [256k][16n] Wih+Whh
        float (*iwc)[260] = (float(*)[260])(smem_raw + 53760);     // [4jj][256r] iw columns
        // stage B (once): bSt[k][n_local] = (Wih+Whh)[n_global][k]  (lane-consecutive)
        #pragma unroll
        for (int n = 0; n < 16; ++n) {
            int nrow = (n >> 2) * 256 + 4 * bid + (n & 3);
            bSt[t][n] = wih[nrow * 256 + t] + whh[nrow * 256 + t];
        }
        // gates GEMM: gates[256m][16n] = iw @ Bsum^T, 4m x 4n / thread
        const int mg = t >> 2, ng = t & 3;
        const int srow = t >> 3, sf4 = t & 7;      // coalesced staging map (128B segments)
        float acc[4][4] = {};
        for (int kt = 0; kt < 8; ++kt) {
            int k0 = kt * 32;
            __syncthreads();
            #pragma unroll
            for (int rr = 0; rr < 8; ++rr) {
                int row = srow + 32 * rr;
                float4 v = *(const float4*)&iw[row * 256 + k0 + 4 * sf4];
                aT[4 * sf4 + 0][row] = v.x; aT[4 * sf4 + 1][row] = v.y;
                aT[4 * sf4 + 2][row] = v.z; aT[4 * sf4 + 3][row] = v.w;
            }
            __syncthreads();
            if (kt == (bid >> 3)) {                // iw cols 4b..4b+3 live in this tile
                int c0 = (4 * bid) & 31;
                #pragma unroll
                for (int jj = 0; jj < 4; ++jj) iwc[jj][t] = aT[c0 + jj][t];
            }
            #pragma unroll 4
            for (int kk = 0; kk < 32; ++kk) {
                float4 a4 = *(const float4*)&aT[kk][4 * mg];
                float4 b4 = *(const float4*)&bSt[k0 + kk][4 * ng];
                float a[4] = {a4.x, a4.y, a4.z, a4.w};
                float b[4] = {b4.x, b4.y, b4.z, b4.w};
                #pragma unroll
                for (int i = 0; i < 4; ++i)
                    #pragma unroll
                    for (int j = 0; j < 4; ++j)
                        acc[i][j] = fmaf(a[i], b[j], acc[i][j]);
            }
        }
        // gates -> LDS (reuse aT region; aT dead)
        float (*gates_lds)[17] = (float(*)[17])smem_raw;           // [256][17]
        float (*wevc)[260]     = (float(*)[260])(smem_raw + 33280);// [4jj][256k]
        __syncthreads();
        #pragma unroll
        for (int i = 0; i < 4; ++i)
            #pragma unroll
            for (int j = 0; j < 4; ++j)
                gates_lds[4 * mg + i][4 * ng + j] = acc[i][j];
        __syncthreads();
        // LSTM nonlinearity (iw column from LDS, no global gather)
        {
            int r = t;
            #pragma unroll
            for (int jj = 0; jj < 4; ++jj) {
                int jcol = 4 * bid + jj;
                float gi = gates_lds[r][0  + jj] + b_ih[jcol]       + b_hh[jcol];
                float gf = gates_lds[r][4  + jj] + b_ih[256 + jcol] + b_hh[256 + jcol];
                float gg = gates_lds[r][8  + jj] + b_ih[512 + jcol] + b_hh[512 + jcol];
                float go = gates_lds[r][12 + jj] + b_ih[768 + jcol] + b_hh[768 + jcol];
                float c  = sig_f(gf) * iwc[jj][r] + sig_f(gi) * tanh_f(gg);
                wevc[jj][r] = sig_f(go) * tanh_f(c);
            }
        }
        // Wc via LDS-staged Wp tiles (coalesced global loads)
        float (*wpT)[132] = (float(*)[132])smem_raw;               // [32kk][128a+pad]
        const int a2 = t & 63, jj = t >> 6;
        float c0 = 0.f, c1 = 0.f;
        for (int kt2 = 0; kt2 < 8; ++kt2) {
            int k0 = kt2 * 32;
            __syncthreads();                       // wpT reuse guard (also closes LSTM)
            #pragma unroll
            for (int ri = 0; ri < 4; ++ri) {
                int a = srow + 32 * ri;            // 0..127
                float4 v = *(const float4*)&Wp[a * 256 + k0 + 4 * sf4];
                wpT[4 * sf4 + 0][a] = v.x; wpT[4 * sf4 + 1][a] = v.y;
                wpT[4 * sf4 + 2][a] = v.z; wpT[4 * sf4 + 3][a] = v.w;
            }
            __syncthreads();
            #pragma unroll 8
            for (int kk = 0; kk < 32; ++kk) {
                float2 wv = *(const float2*)&wpT[kk][2 * a2];
                float wev = wevc[jj][k0 + kk];     // wave-uniform broadcast
                c0 = fmaf(wv.x, wev, c0);
                c1 = fmaf(wv.y, wev, c1);
            }
        }
        wct[(4 * bid + jj) * 64 + a2] = bf16rne(c0) | (bf16rne(c1) << 16);
        if (t < 4) {   // bias column: bc[4b+t] = bp . wevc[t]
            float s = 0.f;
            #pragma unroll 4
            for (int k4 = 0; k4 < 64; ++k4) {
                float4 b4 = *(const float4*)&bp[4 * k4];
                float4 w4 = *(const float4*)&wevc[t][4 * k4];
                s = fmaf(b4.x, w4.x, fmaf(b4.y, w4.y, fmaf(b4.z, w4.z, fmaf(b4.w, w4.w, s))));
            }
            bc[4 * bid + t] = s;
        }
    } else if (bid < NWB + NFB) {
        // wide bucket fill, device-scope atomics (r5-measured ~12us)
        for (int u = (bid - NWB) * 256 + t; u < N_EDGES / 4; u += NFB * 256) {
            int4 s4 = *(const int4*)&ei[u * 4];
            int4 d4 = *(const int4*)&ei[N_EDGES + u * 4];
            int p0 = atomicAdd(&cursor[d4.x], 1);
            if (p0 < CAP) bucket[d4.x * CAP + p0] = s4.x;
            int p1 = atomicAdd(&cursor[d4.y], 1);
            if (p1 < CAP) bucket[d4.y * CAP + p1] = s4.y;
            int p2 = atomicAdd(&cursor[d4.z], 1);
            if (p2 < CAP) bucket[d4.z * CAP + p2] = s4.z;
            int p3 = atomicAdd(&cursor[d4.w], 1);
            if (p3 < CAP) bucket[d4.w * CAP + p3] = s4.w;
        }
    } else {
        // x -> packed bf16x2: 320000 float4 -> uint2, grid-stride over 128 blocks
        const float4* x4 = (const float4*)x;
        uint2* xb2 = (uint2*)xb;
        for (int idx = (bid - NWB - NFB) * 256 + t; idx < N_NODES * 32; idx += NXB * 256) {
            float4 v = x4[idx];
            xb2[idx] = make_uint2(bf16rne(v.x) | (bf16rne(v.y) << 16),
                                  bf16rne(v.z) | (bf16rne(v.w) << 16));
        }
    }
}

// ===== K2: per-tile aggregation (bf16 gathers from L2-resident xb) + MFMA out =====
__global__ __launch_bounds__(256)
void k2_agg_out(const unsigned* __restrict__ xb, const int* __restrict__ cursor,
                const int* __restrict__ bucket, const unsigned* __restrict__ wct,
                const float* __restrict__ bc, const float* __restrict__ b_gcn,
                float* __restrict__ out) {
    __shared__ unsigned y_lds[16][64];   // bf16x2 rows
    __shared__ float rs_lds[16];
    const int t = threadIdx.x;
    const int tile = blockIdx.x;
    const int w = t >> 6, lane = t & 63;
    const int q = lane >> 4, ln = lane & 15;

    for (int vi = 0; vi < 4; ++vi) {
        int r = vi * 4 + w;
        int v = tile * 16 + r;
        int cntv = cursor[v];
        float dv = rsqrtf((float)(cntv + 1));
        int cnt2 = cntv > CAP ? CAP : cntv;
        unsigned self = xb[v * 64 + lane];
        union { unsigned u; float f; } c0, c1;
        c0.u = self << 16; c1.u = self & 0xFFFF0000u;
        float acc0 = dv * c0.f, acc1 = dv * c1.f, wsum = dv;
        const int4* bkt4 = (const int4*)&bucket[v * CAP];
        int j = 0;
        for (; j + 8 <= cnt2; j += 8) {
            int4 sa = bkt4[j >> 2];
            int4 sb = bkt4[(j >> 2) + 1];
            float w0 = rsqrtf((float)(cursor[sa.x] + 1));
            float w1 = rsqrtf((float)(cursor[sa.y] + 1));
            float w2 = rsqrtf((float)(cursor[sa.z] + 1));
            float w3 = rsqrtf((float)(cursor[sa.w] + 1));
            float w4 = rsqrtf((float)(cursor[sb.x] + 1));
            float w5 = rsqrtf((float)(cursor[sb.y] + 1));
            float w6 = rsqrtf((float)(cursor[sb.z] + 1));
            float w7 = rsqrtf((float)(cursor[sb.w] + 1));
            unsigned r0 = xb[sa.x * 64 + lane];
            unsigned r1 = xb[sa.y * 64 + lane];
            unsigned r2 = xb[sa.z * 64 + lane];
            unsigned r3 = xb[sa.w * 64 + lane];
            unsigned r4 = xb[sb.x * 64 + lane];
            unsigned r5 = xb[sb.y * 64 + lane];
            unsigned r6 = xb[sb.z * 64 + lane];
            unsigned r7 = xb[sb.w * 64 + lane];
            union { unsigned u; float f; } a0, a1;
            a0.u = r0 << 16; a1.u = r0 & 0xFFFF0000u;
            acc0 = fmaf(w0, a0.f, acc0); acc1 = fmaf(w0, a1.f, acc1);
            a0.u = r1 << 16; a1.u = r1 & 0xFFFF0000u;
            acc0 = fmaf(w1, a0.f, acc0); acc1 = fmaf(w1, a1.f, acc1);
            a0.u = r2 << 16; a1.u = r2 & 0xFFFF0000u;
            acc0 = fmaf(w2, a0.f, acc0); acc1 = fmaf(w2, a1.f, acc1);
            a0.u = r3 << 16; a1.u = r3 & 0xFFFF0000u;
            acc0 = fmaf(w3, a0.f, acc0); acc1 = fmaf(w3, a1.f, acc1);
            a0.u = r4 << 16; a1.u = r4 & 0xFFFF0000u;
            acc0 = fmaf(w4, a0.f, acc0); acc1 = fmaf(w4, a1.f, acc1);
            a0.u = r5 << 16; a1.u = r5 & 0xFFFF0000u;
            acc0 = fmaf(w5, a0.f, acc0); acc1 = fmaf(w5, a1.f, acc1);
            a0.u = r6 << 16; a1.u = r6 & 0xFFFF0000u;
            acc0 = fmaf(w6, a0.f, acc0); acc1 = fmaf(w6, a1.f, acc1);
            a0.u = r7 << 16; a1.u = r7 & 0xFFFF0000u;
            acc0 = fmaf(w7, a0.f, acc0); acc1 = fmaf(w7, a1.f, acc1);
            wsum += w0 + w1 + w2 + w3 + w4 + w5 + w6 + w7;
        }
        for (; j < cnt2; ++j) {
            int s = bucket[v * CAP + j];
            float ws = rsqrtf((float)(cursor[s] + 1));
            unsigned rr = xb[s * 64 + lane];
            union { unsigned u; float f; } a0, a1;
            a0.u = rr << 16; a1.u = rr & 0xFFFF0000u;
            acc0 = fmaf(ws, a0.f, acc0); acc1 = fmaf(ws, a1.f, acc1);
            wsum += ws;
        }
        y_lds[r][lane] = bf16rne(dv * acc0) | (bf16rne(dv * acc1) << 16);
        if (lane == 0) rs_lds[r] = dv * wsum;
    }
    __syncthreads();

    // MFMA: out_tile[16,256] = y @ WcT^T + rs*bc + b_gcn
    const int4* ya   = (const int4*)&y_lds[0][0];
    const int4* wct4 = (const int4*)wct;
    union { int4 v; frag_ab f; } a[4];
    #pragma unroll
    for (int kc = 0; kc < 4; ++kc)
        a[kc].v = ya[ln * 16 + kc * 4 + q];
    float rsv[4];
    #pragma unroll
    for (int r = 0; r < 4; ++r) rsv[r] = rs_lds[q * 4 + r];
    #pragma unroll
    for (int i = 0; i < 4; ++i) {
        int n0 = (w + 4 * i) * 16;
        union { int4 v; frag_ab f; } b[4];
        #pragma unroll
        for (int kc = 0; kc < 4; ++kc)
            b[kc].v = wct4[(n0 + ln) * 16 + kc * 4 + q];
        frag_cd accd = {0.f, 0.f, 0.f, 0.f};
        #pragma unroll
        for (int kc = 0; kc < 4; ++kc)
            accd = __builtin_amdgcn_mfma_f32_16x16x32_bf16(a[kc].f, b[kc].f, accd, 0, 0, 0);
        int n = n0 + ln;
        float bcv = bc[n], bgv = b_gcn[n];
        #pragma unroll
        for (int r = 0; r < 4; ++r) {
            int m = tile * 16 + q * 4 + r;
            out[m * HID + n] = accd[r] + rsv[r] * bcv + bgv;
        }
    }
}

extern "C" void kernel_launch(void* const* d_in, const int* in_sizes, int n_in,
                              void* d_out, int out_size, void* d_ws, size_t ws_size,
                              hipStream_t stream) {
    const float* x     = (const float*)d_in[0];
    const int*   ei    = (const int*)d_in[1];
    const float* Wp    = (const float*)d_in[2];
    const float* bp    = (const float*)d_in[3];
    const float* W_ih  = (const float*)d_in[4];
    const float* W_hh  = (const float*)d_in[5];
    const float* b_ih  = (const float*)d_in[6];
    const float* b_hh  = (const float*)d_in[7];
    const float* iw    = (const float*)d_in[8];
    const float* b_gcn = (const float*)d_in[9];
    float* out = (float*)d_out;

    char* ws = (char*)d_ws;
    int*      cursor = (int*)     (ws + 0);
    unsigned* wct    = (unsigned*)(ws + 40064);
    float*    bc     = (float*)   (ws + 105600);
    unsigned* xb     = (unsigned*)(ws + 106624);
    int*      bucket = (int*)     (ws + 2666624);

    hipMemsetAsync(cursor, 0, N_NODES * sizeof(int), stream);

    k1_prep<<<NB1, 256, 0, stream>>>(x, ei, Wp, bp, W_ih, W_hh, b_ih, b_hh, iw,
                                     cursor, wct, bc, xb, bucket);
    k2_agg_out<<<625, 256, 0, stream>>>(xb, cursor, bucket, wct, bc, b_gcn, out);
}